// Round 8
// baseline (107.801 us; speedup 1.0000x reference)
//
#include <hip/hip_runtime.h>
#include <math.h>
#include <stdint.h>

#define BB 64
#define DD 512
#define HH 8
#define EPS 1e-8f
#define KCUT 16.0f   // drop j's with softmax exp-arg < -16: mass <= 512*e^-16 ~ 6e-5

// Raw v_rcp_f32 (~1 ulp). Used identically for the softmax max (m) and the
// per-j r, so r-m cancels exactly at the argmin (same instruction, same input).
__device__ __forceinline__ float fast_rcp(float d) {
    return __builtin_amdgcn_rcpf(d);
}

// Block = (b, 64-wide sorted-i window), 512 threads = 8 waves, lane = one i.
// Sorted row => d_j = |a0*x_j + c_i| is V-shaped in j:
//   - argmin (-> m) via 9-step branchless binary search (exact, no dense scan)
//   - contributing j's = contiguous window via 2 more binary searches
// All 8 waves share the same 64 lanes; they take the union window [wlo,whi)
// and each processes an exact 1/8 slice -> no ballots, no wave imbalance.
// j's outside a lane's own window self-suppress (exp2 underflow to 0).
__global__ __launch_bounds__(512, 8) void flattn_kernel(
    const float* __restrict__ x,
    const float* __restrict__ alphas,
    const float* __restrict__ betas,
    float* __restrict__ out)
{
    const int b  = blockIdx.x;
    const int iw = blockIdx.y;           // sorted-i window [iw*64, iw*64+64)

    __shared__ float xs[DD];             // sorted row
    __shared__ int   idxs[DD];           // sorted slot -> original index
    __shared__ float attp[HH][64];       // per-head attended, this i-window
    __shared__ union {
        double kd[DD];                                   // sort keys (4 KB)
        struct { float pss[HH][8][64], psx[HH][8][64]; } g;  // 32 KB
    } u;

    const int tid  = threadIdx.x;
    const int lane = tid & 63;
    const int w    = tid >> 6;           // wave id 0..7

    // ---- rank-sort the row (exact fp64 key = monotone(u32 of x) || index) ----
    const float xv = x[b * DD + tid];
    {
        uint32_t uu  = __float_as_uint(xv);
        uint32_t k32 = (uu & 0x80000000u) ? ~uu : (uu | 0x80000000u);
        u.kd[tid] = (double)k32 + (double)tid * 0.0009765625;  // + tid/1024
    }
    __syncthreads();
    {
        const double mk = u.kd[tid];
        int rank = 0;
        #pragma unroll 8
        for (int j = 0; j < DD; ++j) rank += (u.kd[j] < mk);   // broadcast reads
        __syncthreads();                  // all kd reads done before reuse of u
        xs[rank]   = xv;
        idxs[rank] = tid;
    }
    __syncthreads();

    const float i_x   = xs[iw * 64 + lane];     // this lane's x (sorted order)
    const float scale = 0.04419417382415922f;   // 1/sqrt(512)
    const float log2e = 1.4426950408889634f;

    for (int h = 0; h < HH; ++h) {
        const float a0 = alphas[h * 3 + 0];
        const float a1 = alphas[h * 3 + 1];
        const float b0 = betas[h * 3 + 0];
        const float b1 = betas[h * 3 + 1];
        const float c  = b0 - fmaf(a1, i_x, b1);    // q_j - k_i = a0*x_j + c

        // --- branchless lower_bound for the V-apex x* = -c/a0 ---
        const float a0r   = fast_rcp(a0);           // a0=0 -> inf/NaN: safe below
        const float xstar = -c * a0r;
        int p = 0;
        #pragma unroll
        for (int st = 256; st > 0; st >>= 1) p += (xs[p + st - 1] < xstar) ? st : 0;
        p += (xs[p] < xstar) ? 1 : 0;               // p in [0,512]

        // exact global min from the two neighbors (same fmaf/abs as pass 2)
        const int c0 = p > 0   ? p - 1 : 0;
        const int c1 = p < 512 ? p     : 511;
        const float d0 = fabsf(fmaf(a0, xs[c0], c));
        const float d1 = fabsf(fmaf(a0, xs[c1], c));
        const float gmin = fminf(d0, d1);

        const float m     = fast_rcp(gmin + EPS);   // same expr as pass 2's r
        const float negml = -m * log2e;

        // --- contributing window: |a0*x + c| <= 1/(m-KCUT) ---
        int jlo = 0, jhi = DD;
        const float mr = m - KCUT;
        if (mr > 0.0f) {
            const float dthr = fast_rcp(mr);
            const float xlo = (-c - dthr) * a0r;    // a0 >= 0 (uniform[0,1))
            const float xhi = (-c + dthr) * a0r;    // a0=0: +-inf/NaN -> full
            int q = 0;
            #pragma unroll
            for (int st = 256; st > 0; st >>= 1) q += (xs[q + st - 1] < xlo) ? st : 0;
            q += (xs[q] < xlo) ? 1 : 0;
            jlo = q;
            q = 0;
            #pragma unroll
            for (int st = 256; st > 0; st >>= 1) q += (xs[q + st - 1] < xhi) ? st : 0;
            q += (xs[q] < xhi) ? 1 : 0;
            jhi = q > jlo ? q : jlo + 1;            // window always contains argmin
        }

        // union window across the 64 lanes (same result in every wave)
        int wlo = jlo, whi = jhi;
        #pragma unroll
        for (int off = 32; off > 0; off >>= 1) {
            wlo = min(wlo, __shfl_xor(wlo, off, 64));
            whi = max(whi, __shfl_xor(whi, off, 64));
        }

        // this wave's exact 1/8 slice of the union window
        const int L  = whi - wlo;
        const int js = wlo + ((L * w) >> 3);
        const int je = wlo + ((L * (w + 1)) >> 3);

        float ss = 0.0f, sx = 0.0f;
        for (int j = js; j < je; ++j) {
            const float xj = xs[j];                 // broadcast read
            const float t  = fmaf(a0, xj, c);
            const float r  = fast_rcp(fabsf(t) + EPS);
            const float s  = __builtin_amdgcn_exp2f(fmaf(r, log2e, negml));
            ss += s;
            sx = fmaf(s, xj, sx);
        }
        u.g.pss[h][w][lane] = ss;
        u.g.psx[h][w][lane] = sx;
    }
    __syncthreads();

    // reduce the 8 wave-partials: thread -> (h, ii)
    {
        const int h  = tid >> 6;
        const int ii = tid & 63;
        float ss = 0.0f, sx = 0.0f;
        #pragma unroll
        for (int k = 0; k < 8; ++k) {
            ss += u.g.pss[h][k][ii];
            sx += u.g.psx[h][k][ii];
        }
        const float a2 = alphas[h * 3 + 2];
        const float b2 = betas[h * 3 + 2];
        const float sv = fmaf(a2, sx, b2 * ss);     // vs[] folded out
        attp[h][ii] = sv * fast_rcp(ss) * scale;
    }
    __syncthreads();

    // one plain store per (b, i): residual + all heads (no memset, no atomics)
    if (tid < 64) {
        const int slot = iw * 64 + tid;
        float acc = xs[slot];
        #pragma unroll
        for (int h = 0; h < HH; ++h) acc += attp[h][tid];
        out[b * DD + idxs[slot]] = acc;
    }
}

extern "C" void kernel_launch(void* const* d_in, const int* in_sizes, int n_in,
                              void* d_out, int out_size, void* d_ws, size_t ws_size,
                              hipStream_t stream) {
    const float* x      = (const float*)d_in[0];
    const float* alphas = (const float*)d_in[1];
    const float* betas  = (const float*)d_in[2];
    float* out = (float*)d_out;

    dim3 grid(BB, DD / 64);   // 512 identical blocks
    dim3 block(512);
    flattn_kernel<<<grid, block, 0, stream>>>(x, alphas, betas, out);
}